// Round 13
// baseline (441.456 us; speedup 1.0000x reference)
//
#include <hip/hip_runtime.h>
#include <hip/hip_bf16.h>

// GGCN: g1=relu(A@(x@W1)+b1); g2=relu(A@(g1@W2)+b2); out=relu(g2@Wd1+bd1)@Wd2+bd2
// N=16384, F=32, H=64, A dense f32 (1.07 GB, read 2x -> HBM floor ~341us).
// R13 = R12 (best, 426us, plain loads) with K-step 64->128: each A staging
// instruction = 4 rows x 512B CONTIGUOUS; concurrent row-streams/CU 256->128.
// Clean granule test (prior 512B tests R10/R11 were confounded by NT + B-load
// latency). 4 waves = 2 row-groups x 2 K-halves, 32 rows/wave, 64 tiles/wave,
// barrier-free wave-private pipeline. sA dbuf 64KB + sH SINGLE-buf 64KB
// (per-wave DS program order makes single-buf safe; H loads issued 1 iter
// ahead). In-block split-K=2 reduce + bias + relu (2 end barriers).

typedef __bf16 bf16x8 __attribute__((ext_vector_type(8)));
typedef float  f32x16 __attribute__((ext_vector_type(16)));
typedef float  f32x4v __attribute__((ext_vector_type(4)));
typedef int    i32x4  __attribute__((ext_vector_type(4)));

#define NNODE 16384
#define KDIM  16384
#define HCOL  64

__device__ inline i32x4 pack8(f32x4v a, f32x4v b){
  bf16x8 t;
  t[0]=(__bf16)a[0]; t[1]=(__bf16)a[1]; t[2]=(__bf16)a[2]; t[3]=(__bf16)a[3];
  t[4]=(__bf16)b[0]; t[5]=(__bf16)b[1]; t[6]=(__bf16)b[2]; t[7]=(__bf16)b[3];
  return __builtin_bit_cast(i32x4, t);
}
#define BC(x) __builtin_bit_cast(bf16x8, x)

// ---------------- big kernel: G = relu(A @ Ht^T + bias) ----------------
// block = 256 thr (4 waves = 2 row-groups x 2 K-halves). BM=64. Tile=32r x 128k.
__global__ __launch_bounds__(256, 1) void gcn_layer_kernel(
    const float* __restrict__ A,      // [16384][16384] f32
    const __bf16* __restrict__ Ht,    // [64][16384] bf16 (transposed H)
    const float* __restrict__ bias,   // [64]
    float* __restrict__ G)            // [16384][64] f32
{
  __shared__ i32x4 sA[4*2*512];   // (wid,buf) x 32 rows x 16 chunks = 64 KB
  __shared__ i32x4 sH[4*1024];    // (wid)     x 64 rows x 16 chunks = 64 KB

  const int tid  = threadIdx.x;
  const int lane = tid & 63;
  const int wid  = tid >> 6;
  const int kh   = wid & 1;           // K-half 0/1
  const int rg   = wid >> 1;          // row-group 0/1
  const int row0 = blockIdx.x*64 + rg*32;

  const int srow = lane >> 4;         // 0..3 A staging row-in-group
  const int scol = lane & 15;         // 0..15: 32B f32 slot within 512B row-visit
  const int r    = lane & 31;
  const int hsub = lane >> 5;         // 8-k half of the 16-k MFMA window
  const int x15  = r & 15;

  const int hq   = lane >> 2;         // 0..15 H staging row-in-group
  const int hc   = lane & 3;          // 64B slot within H row's 256B

  const size_t k0 = (size_t)kh * 8192;

  f32x4v ra[16]; i32x4 rh[16];

  const float*  pA0 = A  + (size_t)(row0 + srow)*KDIM + k0 + (size_t)scol*8;
  const __bf16* pH0 = Ht + (size_t)hq*KDIM + k0 + (size_t)hc*32;

  i32x4* sAw = &sA[wid*1024];         // this wave: 2 bufs x 512
  i32x4* sHw = &sH[wid*1024];         // this wave: 64 rows x 16 chunks

  auto loadA = [&](int t){            // 16 instrs, each 4 rows x 512B contig
    const float* p = pA0 + (size_t)t*128;
    #pragma unroll
    for (int pi=0; pi<8; ++pi){       // rows pi*4 + srow
      const float* q = p + (size_t)pi*4*KDIM;
      ra[2*pi]   = *(const f32x4v*)q;            // plain loads (R12-proven)
      ra[2*pi+1] = *(const f32x4v*)(q+4);
    }
  };
  auto loadH = [&](int t){            // 64 rows x 256B, 4 lanes/row x 64B
    const __bf16* p = pH0 + (size_t)t*128;
    #pragma unroll
    for (int hs=0; hs<4; ++hs){       // rows hs*16 + hq
      const __bf16* q = p + (size_t)hs*16*KDIM;
      #pragma unroll
      for (int qq=0; qq<4; ++qq)
        rh[hs*4+qq] = *(const i32x4*)(q + qq*8);
    }
  };
  auto writeA = [&](int buf){
    i32x4* d = sAw + buf*512;
    #pragma unroll
    for (int pi=0; pi<8; ++pi){
      int row = pi*4 + srow;
      d[row*16 + (scol ^ (row & 15))] = pack8(ra[2*pi], ra[2*pi+1]);
    }
  };
  auto writeH = [&](){                // single-buf: program-order after reads
    #pragma unroll
    for (int hs=0; hs<4; ++hs){
      int h = hs*16 + hq;
      #pragma unroll
      for (int qq=0; qq<4; ++qq){
        int c = hc*4 + qq;
        sHw[h*16 + (c ^ (h & 15))] = rh[hs*4+qq];
      }
    }
  };

  f32x16 acc0 = {}, acc1 = {};

  auto compute = [&](int buf){
    const i32x4* bA = sAw + buf*512;
    #pragma unroll
    for (int kk=0; kk<8; ++kk){
      int c = (kk*2 + hsub) ^ x15;               // (r+32)&15 == r&15
      bf16x8 a0 = BC(bA[r*16 + c]);
      bf16x8 b0 = BC(sHw[r*16 + c]);
      bf16x8 b1 = BC(sHw[(r+32)*16 + c]);
      acc0 = __builtin_amdgcn_mfma_f32_32x32x16_bf16(a0, b0, acc0, 0,0,0);
      acc1 = __builtin_amdgcn_mfma_f32_32x32x16_bf16(a0, b1, acc1, 0,0,0);
    }
  };

  // barrier-free per-wave pipeline over 64 tiles (K-half, 128 k each)
  loadA(0); loadH(0);
  writeA(0); writeH();
  loadA(1); loadH(1);
  #pragma unroll 1
  for (int t=0; t<63; ++t){
    compute(t&1);                     // reads sA[buf], sH (tile t)
    writeA((t+1)&1); writeH();        // tile t+1 (regs loaded 1 iter ago)
    if (t < 62){ loadA(t+2); loadH(t+2); }
  }
  compute(1);                         // tile 63

  __syncthreads();                    // cross-wave: red aliases sA regions

  // split-K=2 reduce per row-group: kh=1 dumps, kh=0 combines + bias + relu
  float* red = (float*)sA;            // per rg: 32x64 f32 = 8 KB
  if (kh == 1){
    float* rd = red + rg*2048;
    #pragma unroll
    for (int j=0; j<16; ++j){
      int rr = (j&3) + 8*(j>>2) + 4*hsub;        // C/D layout [verified R1..R12]
      rd[rr*64 + r]      = acc0[j];
      rd[rr*64 + 32 + r] = acc1[j];
    }
  }
  __syncthreads();
  if (kh == 0){
    const float* rd = red + rg*2048;
    #pragma unroll
    for (int j=0; j<16; ++j){
      int rr = (j&3) + 8*(j>>2) + 4*hsub;
      float v0 = acc0[j] + rd[rr*64 + r]      + bias[r];
      float v1 = acc1[j] + rd[rr*64 + 32 + r] + bias[32 + r];
      G[(size_t)(row0 + rr)*HCOL + r]      = fmaxf(v0, 0.f);
      G[(size_t)(row0 + rr)*HCOL + 32 + r] = fmaxf(v1, 0.f);
    }
  }
}

// ---------------- projection: out[h][n] = sum_f in[n][f]*W[f][h], bf16 out ----------------
template<int F>
__global__ __launch_bounds__(128) void proj_T_kernel(
    const float* __restrict__ in,   // [N][F]
    const float* __restrict__ W,    // [F][64]
    __bf16* __restrict__ out)       // [64][N]
{
  constexpr int FP = F + 4;
  __shared__ float sWt[64*FP];
  __shared__ short sOut[64*136];

  int tid = threadIdx.x;
  for (int e = tid; e < 64*F; e += 128){
    int h = e / F, j = e - h*F;
    sWt[h*FP + j] = W[j*64 + h];
  }
  __syncthreads();

  const size_t n = (size_t)blockIdx.x*128 + tid;
  float rowv[F];
  #pragma unroll
  for (int j=0; j<F; j+=4){
    f32x4v v = *(const f32x4v*)(in + n*F + j);
    rowv[j]=v[0]; rowv[j+1]=v[1]; rowv[j+2]=v[2]; rowv[j+3]=v[3];
  }
  #pragma unroll
  for (int h=0; h<64; ++h){
    float s = 0.f;
    #pragma unroll
    for (int j=0; j<F; j+=4){
      f32x4v w = *(const f32x4v*)&sWt[h*FP + j];
      s += rowv[j]*w[0] + rowv[j+1]*w[1] + rowv[j+2]*w[2] + rowv[j+3]*w[3];
    }
    sOut[h*136 + tid] = __builtin_bit_cast(short, (__bf16)s);
  }
  __syncthreads();

  const size_t n0 = (size_t)blockIdx.x*128;
  #pragma unroll
  for (int pi=0; pi<8; ++pi){
    int p = pi*128 + tid;
    int h = p >> 4, cc = p & 15;
    i32x4 v = *(const i32x4*)&sOut[h*136 + cc*8];
    *(i32x4*)(out + (size_t)h*NNODE + n0 + cc*8) = v;
  }
}

// ---------------- tail MLP: out[n] = relu(g2[n]@Wd1+bd1)@Wd2 + bd2 ----------------
__global__ __launch_bounds__(256) void tail_kernel(
    const float* __restrict__ g2,
    const float* __restrict__ Wd1,
    const float* __restrict__ bd1,
    const float* __restrict__ Wd2,
    const float* __restrict__ bd2,
    float* __restrict__ outp)
{
  __shared__ float sW[64*32];
  __shared__ float sb1[32], sw2[32];
  int tid = threadIdx.x;
  for (int e=tid; e<2048; e+=256) sW[e] = Wd1[e];
  if (tid < 32){ sb1[tid] = bd1[tid]; sw2[tid] = Wd2[tid]; }
  __syncthreads();

  size_t n = (size_t)blockIdx.x*256 + tid;
  float rv[64];
  #pragma unroll
  for (int j=0;j<64;j+=4){
    f32x4v v = *(const f32x4v*)(g2 + n*64 + j);
    rv[j]=v[0]; rv[j+1]=v[1]; rv[j+2]=v[2]; rv[j+3]=v[3];
  }
  float o = 0.f;
  #pragma unroll
  for (int c=0;c<32;++c){
    float s = sb1[c];
    #pragma unroll
    for (int j=0;j<64;++j) s += rv[j]*sW[j*32 + c];
    o += fmaxf(s, 0.f) * sw2[c];
  }
  outp[n] = o + bd2[0];
}

extern "C" void kernel_launch(void* const* d_in, const int* in_sizes, int n_in,
                              void* d_out, int out_size, void* d_ws, size_t ws_size,
                              hipStream_t stream)
{
  const float* x   = (const float*)d_in[0];
  const float* a   = (const float*)d_in[1];
  const float* W1  = (const float*)d_in[2];
  const float* b1  = (const float*)d_in[3];
  const float* W2  = (const float*)d_in[4];
  const float* b2  = (const float*)d_in[5];
  const float* Wd1 = (const float*)d_in[6];
  const float* bd1 = (const float*)d_in[7];
  const float* Wd2 = (const float*)d_in[8];
  const float* bd2 = (const float*)d_in[9];
  float* outp = (float*)d_out;

  char* ws = (char*)d_ws;                       // needs 12 MB
  __bf16* Ht1 = (__bf16*)(ws);                  // [64][16384] bf16, 2 MB
  __bf16* Ht2 = (__bf16*)(ws + (2u<<20));       // 2 MB
  float*  g1  = (float*)(ws + (4u<<20));        // [16384][64] f32, 4 MB
  float*  g2  = (float*)(ws + (8u<<20));        // 4 MB

  proj_T_kernel<32><<<128, 128, 0, stream>>>(x,  W1, Ht1);
  gcn_layer_kernel <<<256, 256, 0, stream>>>(a, Ht1, b1, g1);
  proj_T_kernel<64><<<128, 128, 0, stream>>>(g1, W2, Ht2);
  gcn_layer_kernel <<<256, 256, 0, stream>>>(a, Ht2, b2, g2);
  tail_kernel      <<<64, 256, 0, stream>>>(g2, Wd1, bd1, Wd2, bd2, outp);
}